// Round 10
// baseline (210.551 us; speedup 1.0000x reference)
//
#include <hip/hip_runtime.h>
#include <hip/hip_bf16.h>
#include <math.h>

#define N_NODES 50000
#define N_EDGES 800000
#define IN_DIM  128
#define HID_DIM 64

#define NBKT     196        // buckets of 256 nodes: bucket = node >> 8
#define BKT_CAP  5000       // mean 4092, sd 64 -> +14 sigma, safe
#define NPASSC   200        // partition blocks, 4000 edges each
#define EDGES_PER_PASSC (N_EDGES / NPASSC)   // 4000
#define NGEMMB   782        // node groups of 64: ceil(50000/64)

// =============== kernel 1: fused bucket-partition (blocks 0..199) =============
// =============== + gemm h1b = bf16(x @ W1) (blocks 200..981) ==================
// PassC: LDS histogram over 196 buckets, ONE global atomic per (block,bucket)
// to reserve a contiguous run, then write packed edges (src | ldst<<16, ew).
// gemm: block = 64-node group; its 4 waves each own 16 OUTPUT COLUMNS
// (lane = node). Per-lane live state = acc[16] + xk[16] (~40 VGPR) -> fits
// the default 64-VGPR budget, NO scratch spill (R8/R9: acc[64] spilled, 56
// VGPR, 55us scratch-bound). W1[k][jb..jb+16) is wave-uniform -> one
// s_load_dwordx16 per k, consumed as SGPR operand of v_fmac.
__global__ __launch_bounds__(256)
void partgemm_kernel(const int* __restrict__ src, const int* __restrict__ dst,
                     const float* __restrict__ ew, int* __restrict__ gcursor,
                     int2* __restrict__ edge_b,
                     const float* __restrict__ x, const float* __restrict__ W1,
                     unsigned short* __restrict__ h1b) {
    __shared__ int pc_lds[3 * NBKT];         // PassC counters only (~2.3 KB)
    int bid = blockIdx.x;
    int tid = threadIdx.x;
    if (bid < NPASSC) {
        // ---- PassC: partition into buckets ----
        int* cnt1    = pc_lds;               // [196]
        int* cnt2    = cnt1 + NBKT;          // [196]
        int* runbase = cnt2 + NBKT;          // [196]
        if (tid < NBKT) { cnt1[tid] = 0; cnt2[tid] = 0; }
        __syncthreads();
        int e0 = bid * EDGES_PER_PASSC;
        for (int i = tid; i < EDGES_PER_PASSC; i += 256)
            atomicAdd(&cnt1[dst[e0 + i] >> 8], 1);
        __syncthreads();
        if (tid < NBKT) {
            int c = cnt1[tid];
            runbase[tid] = (c > 0) ? atomicAdd(&gcursor[tid], c) : 0;
        }
        __syncthreads();
        for (int i = tid; i < EDGES_PER_PASSC; i += 256) {
            int e = e0 + i;
            int d = dst[e];
            int b = d >> 8;
            int lr = atomicAdd(&cnt2[b], 1);
            int pos = b * BKT_CAP + runbase[b] + lr;
            edge_b[pos] = make_int2(src[e] | ((d & 255) << 16), __float_as_int(ew[e]));
        }
        return;
    }
    // ---- gemm path: lane = node, wave = 16-column slice ----
    int grp  = bid - NPASSC;                 // 0..781, 64 nodes each
    int lane = tid & 63;
    int jb   = (tid >> 6) * 16;              // column base for this wave
    int node = grp * 64 + lane;
    int nclamp = (node < N_NODES) ? node : (N_NODES - 1);
    const float* xr = x + (long)nclamp * IN_DIM;
    float acc[16];
#pragma unroll
    for (int j = 0; j < 16; ++j) acc[j] = 0.0f;
#pragma unroll 1
    for (int kc = 0; kc < IN_DIM; kc += 16) {
        float4 xv0 = *(const float4*)(xr + kc + 0);
        float4 xv1 = *(const float4*)(xr + kc + 4);
        float4 xv2 = *(const float4*)(xr + kc + 8);
        float4 xv3 = *(const float4*)(xr + kc + 12);
        float xk[16] = {xv0.x, xv0.y, xv0.z, xv0.w, xv1.x, xv1.y, xv1.z, xv1.w,
                        xv2.x, xv2.y, xv2.z, xv2.w, xv3.x, xv3.y, xv3.z, xv3.w};
#pragma unroll
        for (int kk = 0; kk < 16; ++kk) {
            const float* wrow = W1 + (kc + kk) * HID_DIM + jb;  // wave-uniform, 64B
            float xs = xk[kk];
#pragma unroll
            for (int j = 0; j < 16; ++j)
                acc[j] += xs * wrow[j];                          // v_fmac, SGPR src
        }
    }
    if (node < N_NODES) {
        unsigned short* outp = h1b + (size_t)node * HID_DIM + jb;
#pragma unroll
        for (int j8 = 0; j8 < 16; j8 += 8) {
            union { uint4 u4; unsigned short s[8]; } p;
#pragma unroll
            for (int t = 0; t < 8; ++t) {
                __hip_bfloat16 b = __float2bfloat16(acc[j8 + t]);
                p.s[t] = *reinterpret_cast<unsigned short*>(&b);
            }
            *reinterpret_cast<uint4*>(outp + j8) = p.u4;         // 16B store
        }
    }
}

// =============== kernel 2: per-bucket fine sort + start/cnt/dinv ==============
// One block per bucket. Per-node count/deg/scan in LDS (no global atomics),
// then scatter edges node-sorted into edge_s (same bucket-region layout).
__global__ __launch_bounds__(256)
void bsort_kernel(const int* __restrict__ gcursor, const int2* __restrict__ edge_b,
                  int2* __restrict__ edge_s, int* __restrict__ start_g,
                  int* __restrict__ cnt_g, float* __restrict__ dinv) {
    __shared__ int   cnt[256];
    __shared__ int   cnt2[256];
    __shared__ float deg[256];
    __shared__ int   sc[256];
    int b   = blockIdx.x;
    int tid = threadIdx.x;
    int M    = gcursor[b];
    int base = b * BKT_CAP;
    cnt[tid] = 0; cnt2[tid] = 0; deg[tid] = 0.0f;
    __syncthreads();
    for (int i = tid; i < M; i += 256) {
        int2 e = edge_b[base + i];
        int ld = (e.x >> 16) & 255;
        atomicAdd(&cnt[ld], 1);
        atomicAdd(&deg[ld], __int_as_float(e.y));
    }
    __syncthreads();
    // exclusive scan of cnt over 256 (Hillis-Steele inclusive, then shift)
    sc[tid] = cnt[tid];
    __syncthreads();
#pragma unroll
    for (int off = 1; off < 256; off <<= 1) {
        int t = (tid >= off) ? sc[tid - off] : 0;
        __syncthreads();
        sc[tid] += t;
        __syncthreads();
    }
    int startL = sc[tid] - cnt[tid];         // exclusive
    int node = b * 256 + tid;
    if (node < N_NODES) {
        start_g[node] = base + startL;
        cnt_g[node]   = cnt[tid];
        dinv[node]    = rsqrtf(1.0f + deg[tid]);
    }
    // stash exclusive offsets for the scatter phase
    sc[tid] = startL;
    __syncthreads();
    for (int i = tid; i < M; i += 256) {
        int2 e = edge_b[base + i];
        int ld = (e.x >> 16) & 255;
        int r = atomicAdd(&cnt2[ld], 1);
        edge_s[base + sc[ld] + r] = make_int2(e.x & 0xFFFF, e.y);
    }
}

// =============== kernel 3: gather L1 + finalize + relu + W2 GEMV ==============
// wave per node, lane = column; dinv[src] folded during LDS staging.
__global__ void gather1_layer2_kernel(const int* __restrict__ start_g, const int* __restrict__ cnt_g,
                                      const int2* __restrict__ edge_s,
                                      const __hip_bfloat16* __restrict__ h1b,
                                      const float* __restrict__ dinv, const float* __restrict__ b1,
                                      const float* __restrict__ W2, float* __restrict__ h2s) {
    __shared__ int2 meta[4][64];
    int wave = (blockIdx.x * blockDim.x + threadIdx.x) >> 6;
    int wl = threadIdx.x >> 6;
    int lane = threadIdx.x & 63;
    if (wave >= N_NODES) return;
    int s0 = start_g[wave];
    int ctotal = cnt_g[wave];
    float acc0 = 0.f, acc1 = 0.f, acc2 = 0.f, acc3 = 0.f;
    for (int done = 0; done < ctotal; done += 64) {
        int cnt = ctotal - done;
        if (cnt > 64) cnt = 64;
        if (lane < cnt) {
            int2 m = edge_s[s0 + done + lane];
            float w = __int_as_float(m.y) * dinv[m.x];   // fold dinv[src]
            meta[wl][lane] = make_int2(m.x, __float_as_int(w));
        }
        __builtin_amdgcn_wave_barrier();
        int j = 0;
        for (; j + 8 <= cnt; j += 8) {
            int2 m0 = meta[wl][j + 0];
            int2 m1 = meta[wl][j + 1];
            int2 m2 = meta[wl][j + 2];
            int2 m3 = meta[wl][j + 3];
            int2 m4 = meta[wl][j + 4];
            int2 m5 = meta[wl][j + 5];
            int2 m6 = meta[wl][j + 6];
            int2 m7 = meta[wl][j + 7];
            float v0 = __bfloat162float(h1b[m0.x * HID_DIM + lane]);
            float v1 = __bfloat162float(h1b[m1.x * HID_DIM + lane]);
            float v2 = __bfloat162float(h1b[m2.x * HID_DIM + lane]);
            float v3 = __bfloat162float(h1b[m3.x * HID_DIM + lane]);
            float v4 = __bfloat162float(h1b[m4.x * HID_DIM + lane]);
            float v5 = __bfloat162float(h1b[m5.x * HID_DIM + lane]);
            float v6 = __bfloat162float(h1b[m6.x * HID_DIM + lane]);
            float v7 = __bfloat162float(h1b[m7.x * HID_DIM + lane]);
            acc0 += __int_as_float(m0.y) * v0;
            acc1 += __int_as_float(m1.y) * v1;
            acc2 += __int_as_float(m2.y) * v2;
            acc3 += __int_as_float(m3.y) * v3;
            acc0 += __int_as_float(m4.y) * v4;
            acc1 += __int_as_float(m5.y) * v5;
            acc2 += __int_as_float(m6.y) * v6;
            acc3 += __int_as_float(m7.y) * v7;
        }
        for (; j + 2 <= cnt; j += 2) {
            int2 m0 = meta[wl][j + 0];
            int2 m1 = meta[wl][j + 1];
            float v0 = __bfloat162float(h1b[m0.x * HID_DIM + lane]);
            float v1 = __bfloat162float(h1b[m1.x * HID_DIM + lane]);
            acc0 += __int_as_float(m0.y) * v0;
            acc1 += __int_as_float(m1.y) * v1;
        }
        if (j < cnt) {
            int2 m = meta[wl][j];
            acc0 += __int_as_float(m.y) * __bfloat162float(h1b[m.x * HID_DIM + lane]);
        }
        __builtin_amdgcn_wave_barrier();
    }
    float di = dinv[wave];
    float self = __bfloat162float(h1b[wave * HID_DIM + lane]);   // unscaled
    float z = di * (acc0 + acc1 + acc2 + acc3 + di * self) + b1[lane];
    float h = fmaxf(z, 0.0f);
    float v = h * W2[lane];
#pragma unroll
    for (int off = 32; off > 0; off >>= 1)
        v += __shfl_down(v, off, 64);
    if (lane == 0) h2s[wave] = v * di;
}

// =============== kernel 4: gather L2 + sigmoid ================================
__global__ void gather2_final_kernel(const int* __restrict__ start_g, const int* __restrict__ cnt_g,
                                     const int2* __restrict__ edge_s,
                                     const float* __restrict__ h2s, const float* __restrict__ dinv,
                                     const float* __restrict__ b2, float* __restrict__ out) {
    int n = blockIdx.x * blockDim.x + threadIdx.x;
    if (n >= N_NODES) return;
    int s0 = start_g[n];
    int s1 = s0 + cnt_g[n];
    float acc = 0.0f;
    for (int t = s0; t < s1; ++t) {
        int2 m = edge_s[t];
        acc += __int_as_float(m.y) * h2s[m.x];
    }
    float z = dinv[n] * (acc + h2s[n]) + b2[0];
    out[n] = 1.0f / (1.0f + expf(-z));
}

extern "C" void kernel_launch(void* const* d_in, const int* in_sizes, int n_in,
                              void* d_out, int out_size, void* d_ws, size_t ws_size,
                              hipStream_t stream) {
    const float* x  = (const float*)d_in[0];
    const int*   ei = (const int*)d_in[1];
    const float* ew = (const float*)d_in[2];
    const float* W1 = (const float*)d_in[3];
    const float* b1 = (const float*)d_in[4];
    const float* W2 = (const float*)d_in[5];
    const float* b2 = (const float*)d_in[6];
    float* out = (float*)d_out;

    const int* src = ei;
    const int* dst = ei + N_EDGES;

    // workspace layout (int2 arrays first for 8B alignment)
    char* ws = (char*)d_ws;
    int2*  edge_b  = (int2*)ws;              ws += (size_t)NBKT * BKT_CAP * sizeof(int2);
    int2*  edge_s  = (int2*)ws;              ws += (size_t)NBKT * BKT_CAP * sizeof(int2);
    int*   gcursor = (int*)ws;               ws += NBKT * sizeof(int);
    int*   start_g = (int*)ws;               ws += N_NODES * sizeof(int);
    int*   cnt_g   = (int*)ws;               ws += N_NODES * sizeof(int);
    float* dinv    = (float*)ws;             ws += N_NODES * sizeof(float);
    float* h2s     = (float*)ws;             ws += N_NODES * sizeof(float);
    unsigned short* h1b = (unsigned short*)ws;  // N_NODES * HID_DIM bf16 bits

    hipMemsetAsync(gcursor, 0, NBKT * sizeof(int), stream);
    partgemm_kernel<<<NPASSC + NGEMMB, 256, 0, stream>>>(src, dst, ew, gcursor, edge_b, x, W1, h1b);
    bsort_kernel<<<NBKT, 256, 0, stream>>>(gcursor, edge_b, edge_s, start_g, cnt_g, dinv);
    gather1_layer2_kernel<<<(N_NODES * 64) / 256, 256, 0, stream>>>(start_g, cnt_g, edge_s,
                                                                    (const __hip_bfloat16*)h1b,
                                                                    dinv, b1, W2, h2s);
    gather2_final_kernel<<<(N_NODES + 255) / 256, 256, 0, stream>>>(start_g, cnt_g, edge_s, h2s, dinv, b2, out);
}

// Round 11
// 164.580 us; speedup vs baseline: 1.2793x; 1.2793x over previous
//
#include <hip/hip_runtime.h>
#include <hip/hip_bf16.h>
#include <math.h>

#define N_NODES 50000
#define N_EDGES 800000
#define IN_DIM  128
#define HID_DIM 64

#define NBKT     196        // buckets of 256 nodes: bucket = node >> 8
#define BKT_CAP  5000       // mean 4092, sd 64 -> +14 sigma, safe
#define NPASSC   200        // partition blocks, 4000 edges each
#define EDGES_PER_PASSC (N_EDGES / NPASSC)   // 4000
#define NGEMMB   782        // node groups of 64: ceil(50000/64)

// =============== kernel 1: fused bucket-partition (blocks 0..199) =============
// =============== + gemm h1b = bf16(x @ W1) (blocks 200..981) ==================
// PassC: LDS histogram over 196 buckets, ONE global atomic per (block,bucket)
// to reserve a contiguous run, then write packed edges (src | ldst<<16, ew).
// gemm: block = 64-node group; its 4 waves each own 16 OUTPUT COLUMNS
// (lane = node). acc[16]+xk[16] ~= 40 VGPR: no spill (R8/R9 lesson).
// jb is forced uniform via readfirstlane so the W1 slice address is provably
// scalar -> s_load_dwordx16 on the scalar pipe (R10 lesson: tid-derived jb
// made W1 reads per-lane VMEM broadcasts, 80us).
__global__ __launch_bounds__(256)
void partgemm_kernel(const int* __restrict__ src, const int* __restrict__ dst,
                     const float* __restrict__ ew, int* __restrict__ gcursor,
                     int2* __restrict__ edge_b,
                     const float* __restrict__ x, const float* __restrict__ W1,
                     unsigned short* __restrict__ h1b) {
    __shared__ int pc_lds[3 * NBKT];         // PassC counters only (~2.3 KB)
    int bid = blockIdx.x;
    int tid = threadIdx.x;
    if (bid < NPASSC) {
        // ---- PassC: partition into buckets ----
        int* cnt1    = pc_lds;               // [196]
        int* cnt2    = cnt1 + NBKT;          // [196]
        int* runbase = cnt2 + NBKT;          // [196]
        if (tid < NBKT) { cnt1[tid] = 0; cnt2[tid] = 0; }
        __syncthreads();
        int e0 = bid * EDGES_PER_PASSC;
        for (int i = tid; i < EDGES_PER_PASSC; i += 256)
            atomicAdd(&cnt1[dst[e0 + i] >> 8], 1);
        __syncthreads();
        if (tid < NBKT) {
            int c = cnt1[tid];
            runbase[tid] = (c > 0) ? atomicAdd(&gcursor[tid], c) : 0;
        }
        __syncthreads();
        for (int i = tid; i < EDGES_PER_PASSC; i += 256) {
            int e = e0 + i;
            int d = dst[e];
            int b = d >> 8;
            int lr = atomicAdd(&cnt2[b], 1);
            int pos = b * BKT_CAP + runbase[b] + lr;
            edge_b[pos] = make_int2(src[e] | ((d & 255) << 16), __float_as_int(ew[e]));
        }
        return;
    }
    // ---- gemm path: lane = node, wave = 16-column slice ----
    int grp  = bid - NPASSC;                 // 0..781, 64 nodes each
    int lane = tid & 63;
    int jb   = __builtin_amdgcn_readfirstlane((tid >> 6) * 16);  // FORCE uniform
    int node = grp * 64 + lane;
    int nclamp = (node < N_NODES) ? node : (N_NODES - 1);
    const float* xr = x + (long)nclamp * IN_DIM;
    const float* Wb = W1 + jb;               // scalar base
    float acc[16];
#pragma unroll
    for (int j = 0; j < 16; ++j) acc[j] = 0.0f;
#pragma unroll 1
    for (int kc = 0; kc < IN_DIM; kc += 16) {
        float4 xv0 = *(const float4*)(xr + kc + 0);
        float4 xv1 = *(const float4*)(xr + kc + 4);
        float4 xv2 = *(const float4*)(xr + kc + 8);
        float4 xv3 = *(const float4*)(xr + kc + 12);
        float xk[16] = {xv0.x, xv0.y, xv0.z, xv0.w, xv1.x, xv1.y, xv1.z, xv1.w,
                        xv2.x, xv2.y, xv2.z, xv2.w, xv3.x, xv3.y, xv3.z, xv3.w};
#pragma unroll
        for (int kk = 0; kk < 16; ++kk) {
            const float* wrow = Wb + (kc + kk) * HID_DIM;   // scalar addr -> s_load
            float xs = xk[kk];
#pragma unroll
            for (int j = 0; j < 16; ++j)
                acc[j] += xs * wrow[j];                      // v_fmac, SGPR src
        }
    }
    if (node < N_NODES) {
        unsigned short* outp = h1b + (size_t)node * HID_DIM + jb;
#pragma unroll
        for (int j8 = 0; j8 < 16; j8 += 8) {
            union { uint4 u4; unsigned short s[8]; } p;
#pragma unroll
            for (int t = 0; t < 8; ++t) {
                __hip_bfloat16 b = __float2bfloat16(acc[j8 + t]);
                p.s[t] = *reinterpret_cast<unsigned short*>(&b);
            }
            *reinterpret_cast<uint4*>(outp + j8) = p.u4;     // 16B store
        }
    }
}

// =============== kernel 2: per-bucket fine sort + start/cnt/dinv ==============
// One block per bucket. Per-node count/deg/scan in LDS (no global atomics),
// then scatter edges node-sorted into edge_s (same bucket-region layout).
__global__ __launch_bounds__(256)
void bsort_kernel(const int* __restrict__ gcursor, const int2* __restrict__ edge_b,
                  int2* __restrict__ edge_s, int* __restrict__ start_g,
                  int* __restrict__ cnt_g, float* __restrict__ dinv) {
    __shared__ int   cnt[256];
    __shared__ int   cnt2[256];
    __shared__ float deg[256];
    __shared__ int   sc[256];
    int b   = blockIdx.x;
    int tid = threadIdx.x;
    int M    = gcursor[b];
    int base = b * BKT_CAP;
    cnt[tid] = 0; cnt2[tid] = 0; deg[tid] = 0.0f;
    __syncthreads();
    for (int i = tid; i < M; i += 256) {
        int2 e = edge_b[base + i];
        int ld = (e.x >> 16) & 255;
        atomicAdd(&cnt[ld], 1);
        atomicAdd(&deg[ld], __int_as_float(e.y));
    }
    __syncthreads();
    // exclusive scan of cnt over 256 (Hillis-Steele inclusive, then shift)
    sc[tid] = cnt[tid];
    __syncthreads();
#pragma unroll
    for (int off = 1; off < 256; off <<= 1) {
        int t = (tid >= off) ? sc[tid - off] : 0;
        __syncthreads();
        sc[tid] += t;
        __syncthreads();
    }
    int startL = sc[tid] - cnt[tid];         // exclusive
    int node = b * 256 + tid;
    if (node < N_NODES) {
        start_g[node] = base + startL;
        cnt_g[node]   = cnt[tid];
        dinv[node]    = rsqrtf(1.0f + deg[tid]);
    }
    // stash exclusive offsets for the scatter phase
    sc[tid] = startL;
    __syncthreads();
    for (int i = tid; i < M; i += 256) {
        int2 e = edge_b[base + i];
        int ld = (e.x >> 16) & 255;
        int r = atomicAdd(&cnt2[ld], 1);
        edge_s[base + sc[ld] + r] = make_int2(e.x & 0xFFFF, e.y);
    }
}

// =============== kernel 3: gather L1 + finalize + relu + W2 GEMV ==============
// wave per node, lane = column; dinv[src] folded during LDS staging.
__global__ void gather1_layer2_kernel(const int* __restrict__ start_g, const int* __restrict__ cnt_g,
                                      const int2* __restrict__ edge_s,
                                      const __hip_bfloat16* __restrict__ h1b,
                                      const float* __restrict__ dinv, const float* __restrict__ b1,
                                      const float* __restrict__ W2, float* __restrict__ h2s) {
    __shared__ int2 meta[4][64];
    int wave = (blockIdx.x * blockDim.x + threadIdx.x) >> 6;
    int wl = threadIdx.x >> 6;
    int lane = threadIdx.x & 63;
    if (wave >= N_NODES) return;
    int s0 = start_g[wave];
    int ctotal = cnt_g[wave];
    float acc0 = 0.f, acc1 = 0.f, acc2 = 0.f, acc3 = 0.f;
    for (int done = 0; done < ctotal; done += 64) {
        int cnt = ctotal - done;
        if (cnt > 64) cnt = 64;
        if (lane < cnt) {
            int2 m = edge_s[s0 + done + lane];
            float w = __int_as_float(m.y) * dinv[m.x];   // fold dinv[src]
            meta[wl][lane] = make_int2(m.x, __float_as_int(w));
        }
        __builtin_amdgcn_wave_barrier();
        int j = 0;
        for (; j + 8 <= cnt; j += 8) {
            int2 m0 = meta[wl][j + 0];
            int2 m1 = meta[wl][j + 1];
            int2 m2 = meta[wl][j + 2];
            int2 m3 = meta[wl][j + 3];
            int2 m4 = meta[wl][j + 4];
            int2 m5 = meta[wl][j + 5];
            int2 m6 = meta[wl][j + 6];
            int2 m7 = meta[wl][j + 7];
            float v0 = __bfloat162float(h1b[m0.x * HID_DIM + lane]);
            float v1 = __bfloat162float(h1b[m1.x * HID_DIM + lane]);
            float v2 = __bfloat162float(h1b[m2.x * HID_DIM + lane]);
            float v3 = __bfloat162float(h1b[m3.x * HID_DIM + lane]);
            float v4 = __bfloat162float(h1b[m4.x * HID_DIM + lane]);
            float v5 = __bfloat162float(h1b[m5.x * HID_DIM + lane]);
            float v6 = __bfloat162float(h1b[m6.x * HID_DIM + lane]);
            float v7 = __bfloat162float(h1b[m7.x * HID_DIM + lane]);
            acc0 += __int_as_float(m0.y) * v0;
            acc1 += __int_as_float(m1.y) * v1;
            acc2 += __int_as_float(m2.y) * v2;
            acc3 += __int_as_float(m3.y) * v3;
            acc0 += __int_as_float(m4.y) * v4;
            acc1 += __int_as_float(m5.y) * v5;
            acc2 += __int_as_float(m6.y) * v6;
            acc3 += __int_as_float(m7.y) * v7;
        }
        for (; j + 2 <= cnt; j += 2) {
            int2 m0 = meta[wl][j + 0];
            int2 m1 = meta[wl][j + 1];
            float v0 = __bfloat162float(h1b[m0.x * HID_DIM + lane]);
            float v1 = __bfloat162float(h1b[m1.x * HID_DIM + lane]);
            acc0 += __int_as_float(m0.y) * v0;
            acc1 += __int_as_float(m1.y) * v1;
        }
        if (j < cnt) {
            int2 m = meta[wl][j];
            acc0 += __int_as_float(m.y) * __bfloat162float(h1b[m.x * HID_DIM + lane]);
        }
        __builtin_amdgcn_wave_barrier();
    }
    float di = dinv[wave];
    float self = __bfloat162float(h1b[wave * HID_DIM + lane]);   // unscaled
    float z = di * (acc0 + acc1 + acc2 + acc3 + di * self) + b1[lane];
    float h = fmaxf(z, 0.0f);
    float v = h * W2[lane];
#pragma unroll
    for (int off = 32; off > 0; off >>= 1)
        v += __shfl_down(v, off, 64);
    if (lane == 0) h2s[wave] = v * di;
}

// =============== kernel 4: gather L2 + sigmoid ================================
__global__ void gather2_final_kernel(const int* __restrict__ start_g, const int* __restrict__ cnt_g,
                                     const int2* __restrict__ edge_s,
                                     const float* __restrict__ h2s, const float* __restrict__ dinv,
                                     const float* __restrict__ b2, float* __restrict__ out) {
    int n = blockIdx.x * blockDim.x + threadIdx.x;
    if (n >= N_NODES) return;
    int s0 = start_g[n];
    int s1 = s0 + cnt_g[n];
    float acc = 0.0f;
    for (int t = s0; t < s1; ++t) {
        int2 m = edge_s[t];
        acc += __int_as_float(m.y) * h2s[m.x];
    }
    float z = dinv[n] * (acc + h2s[n]) + b2[0];
    out[n] = 1.0f / (1.0f + expf(-z));
}

extern "C" void kernel_launch(void* const* d_in, const int* in_sizes, int n_in,
                              void* d_out, int out_size, void* d_ws, size_t ws_size,
                              hipStream_t stream) {
    const float* x  = (const float*)d_in[0];
    const int*   ei = (const int*)d_in[1];
    const float* ew = (const float*)d_in[2];
    const float* W1 = (const float*)d_in[3];
    const float* b1 = (const float*)d_in[4];
    const float* W2 = (const float*)d_in[5];
    const float* b2 = (const float*)d_in[6];
    float* out = (float*)d_out;

    const int* src = ei;
    const int* dst = ei + N_EDGES;

    // workspace layout (int2 arrays first for 8B alignment)
    char* ws = (char*)d_ws;
    int2*  edge_b  = (int2*)ws;              ws += (size_t)NBKT * BKT_CAP * sizeof(int2);
    int2*  edge_s  = (int2*)ws;              ws += (size_t)NBKT * BKT_CAP * sizeof(int2);
    int*   gcursor = (int*)ws;               ws += NBKT * sizeof(int);
    int*   start_g = (int*)ws;               ws += N_NODES * sizeof(int);
    int*   cnt_g   = (int*)ws;               ws += N_NODES * sizeof(int);
    float* dinv    = (float*)ws;             ws += N_NODES * sizeof(float);
    float* h2s     = (float*)ws;             ws += N_NODES * sizeof(float);
    unsigned short* h1b = (unsigned short*)ws;  // N_NODES * HID_DIM bf16 bits

    hipMemsetAsync(gcursor, 0, NBKT * sizeof(int), stream);
    partgemm_kernel<<<NPASSC + NGEMMB, 256, 0, stream>>>(src, dst, ew, gcursor, edge_b, x, W1, h1b);
    bsort_kernel<<<NBKT, 256, 0, stream>>>(gcursor, edge_b, edge_s, start_g, cnt_g, dinv);
    gather1_layer2_kernel<<<(N_NODES * 64) / 256, 256, 0, stream>>>(start_g, cnt_g, edge_s,
                                                                    (const __hip_bfloat16*)h1b,
                                                                    dinv, b1, W2, h2s);
    gather2_final_kernel<<<(N_NODES + 255) / 256, 256, 0, stream>>>(start_g, cnt_g, edge_s, h2s, dinv, b2, out);
}